// Round 9
// baseline (567.130 us; speedup 1.0000x reference)
//
#include <hip/hip_runtime.h>

#define HW   4096
#define CIN  32
#define NB   1024   // grid size; 4 blocks/CU x 256 CU -- co-residency by construction
// scale in log2 domain: (1/sqrt(NCLASS)) * log2(e); NCLASS = 2
#define SCALE2 (0.70710678118654752f * 1.44269504088896340f)

// Raw v_exp_f32 (2^x): args bounded (|x| <~ 12), skip libm denormal fixup.
__device__ __forceinline__ float exp2_raw(float x) {
#if __has_builtin(__builtin_amdgcn_exp2f)
    return __builtin_amdgcn_exp2f(x);
#else
    float r;
    asm("v_exp_f32 %0, %1" : "=v"(r) : "v"(x));
    return r;
#endif
}

// Device-scope grid barrier. bar points at a zeroed (per-launch memset) region:
//   bar[shard*16]  : 32 shard counters, 64B apart (avoid same-line atomic serialization)
//   bar[32*16]     : root counter
//   bar[33*16]     : release flag
__device__ __forceinline__ void grid_barrier(int* bar) {
    __threadfence();
    __syncthreads();
    if (threadIdx.x == 0) {
        int* flag = bar + 33 * 16;
        int old = __hip_atomic_fetch_add(bar + (blockIdx.x & 31) * 16, 1,
                                         __ATOMIC_ACQ_REL, __HIP_MEMORY_SCOPE_AGENT);
        if (old == (NB / 32) - 1) {
            int o2 = __hip_atomic_fetch_add(bar + 32 * 16, 1,
                                            __ATOMIC_ACQ_REL, __HIP_MEMORY_SCOPE_AGENT);
            if (o2 == 31)
                __hip_atomic_store(flag, 1, __ATOMIC_RELEASE, __HIP_MEMORY_SCOPE_AGENT);
        }
        while (__hip_atomic_load(flag, __ATOMIC_ACQUIRE, __HIP_MEMORY_SCOPE_AGENT) == 0)
            __builtin_amdgcn_s_sleep(2);
    }
    __syncthreads();
    __threadfence();
}

// One dispatch, 3 phases. Block b owns 16 columns: n = b>>8, pg = (b&255)*16.
//   A: project its 16 columns -> f1 (LDS, pre-scaled), f2 (LDS + global f2v)
//   B: l[p] = sum_q 2^(f1[p].f2[q]) -> stats4 {f1x, f1y, V0/l, V1/l} (global)
//   C: o[c,q] = sum_p stats.zw * 2^(stats.xy . f2[q])
__global__ __launch_bounds__(256, 4) void fused_corr_kernel(
        const float* __restrict__ feat, const float* __restrict__ outv,
        const float* __restrict__ w1, const float* __restrict__ b1,
        const float* __restrict__ w2, const float* __restrict__ b2,
        float2* __restrict__ f2v, float4* __restrict__ stats4,
        int* __restrict__ bar, float* __restrict__ o) {
    __shared__ float4 redA[4][16];
    __shared__ float  redB[4][16];
    __shared__ float  redC[4][16][2];
    __shared__ float2 sf1[16];    // f1 of this block's 16 cols, pre-scaled
    __shared__ float2 sg[16];     // f2 of this block's 16 cols

    int tid = threadIdx.x;
    int lane = tid & 63;
    int wid = tid >> 6;
    int b = blockIdx.x;
    int n = b >> 8;
    int pg = (b & 255) << 4;
    int base = n * HW;

    // ---------------- Phase A: projections for our 16 columns ----------------
    {
        int j = tid & 15;              // column
        int c0 = (tid >> 4) << 1;      // 2 channels per thread
        const float* fb = feat + ((size_t)n * CIN + c0) * HW + pg + j;
        float v0 = fb[0], v1 = fb[HW];
        float a10 = v0 * w1[c0]      + v1 * w1[c0 + 1];
        float a11 = v0 * w1[32 + c0] + v1 * w1[32 + c0 + 1];
        float a20 = v0 * w2[c0]      + v1 * w2[c0 + 1];
        float a21 = v0 * w2[32 + c0] + v1 * w2[32 + c0 + 1];
        // reduce the 4 channel-groups within this wave (lanes j, j^16, j^32, j^48)
        a10 += __shfl_xor(a10, 16); a10 += __shfl_xor(a10, 32);
        a11 += __shfl_xor(a11, 16); a11 += __shfl_xor(a11, 32);
        a20 += __shfl_xor(a20, 16); a20 += __shfl_xor(a20, 32);
        a21 += __shfl_xor(a21, 16); a21 += __shfl_xor(a21, 32);
        if (lane < 16) redA[wid][lane] = make_float4(a10, a11, a20, a21);
        __syncthreads();
        if (tid < 16) {
            float4 r0 = redA[0][tid], r1 = redA[1][tid], r2 = redA[2][tid], r3 = redA[3][tid];
            float2 f1 = make_float2((r0.x + r1.x + r2.x + r3.x + b1[0]) * SCALE2,
                                    (r0.y + r1.y + r2.y + r3.y + b1[1]) * SCALE2);
            float2 f2 = make_float2(r0.z + r1.z + r2.z + r3.z + b2[0],
                                    r0.w + r1.w + r2.w + r3.w + b2[1]);
            sf1[tid] = f1;
            sg[tid] = f2;
            f2v[base + pg + tid] = f2;
        }
    }
    grid_barrier(bar);                 // publish f2v

    // ---------------- Phase B: rowstats for our 16 p's ----------------
    {
        float f10[16], f11[16];
#pragma unroll
        for (int j = 0; j < 16; ++j) { // LDS broadcast -> registers
            float2 t = sf1[j];
            f10[j] = t.x; f11[j] = t.y;
        }
        const float4* f2b = (const float4*)(f2v + base) + wid * 512 + lane;
        float acc[16];
#pragma unroll
        for (int j = 0; j < 16; ++j) acc[j] = 0.f;
        float4 cur = f2b[0];
#pragma unroll
        for (int s = 0; s < 8; ++s) {
            float4 nxt = f2b[((s + 1) & 7) * 64];   // distance-1 rotation
#pragma unroll
            for (int j = 0; j < 16; ++j) {
                float e0 = exp2_raw(f10[j] * cur.x + f11[j] * cur.y);
                float e1 = exp2_raw(f10[j] * cur.z + f11[j] * cur.w);
                acc[j] += e0 + e1;
            }
            cur = nxt;
        }
#pragma unroll
        for (int j = 0; j < 16; ++j) {
            float a = acc[j];
            a += __shfl_xor(a, 1);  a += __shfl_xor(a, 2);
            a += __shfl_xor(a, 4);  a += __shfl_xor(a, 8);
            a += __shfl_xor(a, 16); a += __shfl_xor(a, 32);
            acc[j] = a;
        }
        if (lane == 0) {
#pragma unroll
            for (int j = 0; j < 16; ++j) redB[wid][j] = acc[j];
        }
        __syncthreads();
        if (tid < 16) {
            float lt = redB[0][tid] + redB[1][tid] + redB[2][tid] + redB[3][tid];
            float inv = 1.0f / lt;
            int pp = pg + tid;
            float2 f1 = sf1[tid];
            float v0 = outv[(n * 2 + 0) * HW + pp];
            float v1 = outv[(n * 2 + 1) * HW + pp];
            stats4[base + pp] = make_float4(f1.x, f1.y, v0 * inv, v1 * inv);
        }
    }
    grid_barrier(bar + 1024);          // publish stats4

    // ---------------- Phase C: colout for our 16 q's ----------------
    {
        float g0[16], g1[16];
#pragma unroll
        for (int j = 0; j < 16; ++j) { // LDS broadcast -> registers
            float2 t = sg[j];
            g0[j] = t.x; g1[j] = t.y;
        }
        const float4* stb = stats4 + base + wid * 1024 + lane;
        float o0[16], o1[16];
#pragma unroll
        for (int j = 0; j < 16; ++j) { o0[j] = 0.f; o1[j] = 0.f; }
        float4 cur = stb[0];
#pragma unroll
        for (int s = 0; s < 16; ++s) {
            float4 nxt = stb[((s + 1) & 15) * 64];  // distance-1 rotation
#pragma unroll
            for (int j = 0; j < 16; ++j) {
                float e = exp2_raw(g0[j] * cur.x + g1[j] * cur.y);
                o0[j] += cur.z * e;
                o1[j] += cur.w * e;
            }
            cur = nxt;
        }
#pragma unroll
        for (int j = 0; j < 16; ++j) {
            float a = o0[j], c = o1[j];
            a += __shfl_xor(a, 1);  c += __shfl_xor(c, 1);
            a += __shfl_xor(a, 2);  c += __shfl_xor(c, 2);
            a += __shfl_xor(a, 4);  c += __shfl_xor(c, 4);
            a += __shfl_xor(a, 8);  c += __shfl_xor(c, 8);
            a += __shfl_xor(a, 16); c += __shfl_xor(c, 16);
            a += __shfl_xor(a, 32); c += __shfl_xor(c, 32);
            o0[j] = a; o1[j] = c;
        }
        if (lane == 0) {
#pragma unroll
            for (int j = 0; j < 16; ++j) { redC[wid][j][0] = o0[j]; redC[wid][j][1] = o1[j]; }
        }
        __syncthreads();
        if (tid < 32) {
            int qq = tid >> 1, c = tid & 1;
            float r = redC[0][qq][c] + redC[1][qq][c] + redC[2][qq][c] + redC[3][qq][c];
            o[(n * 2 + c) * HW + pg + qq] = r;
        }
    }
}

extern "C" void kernel_launch(void* const* d_in, const int* in_sizes, int n_in,
                              void* d_out, int out_size, void* d_ws, size_t ws_size,
                              hipStream_t stream) {
    const float* feat = (const float*)d_in[0];   // (4,32,64,64)
    const float* outv = (const float*)d_in[1];   // (4,2,64,64)
    const float* w1   = (const float*)d_in[2];   // (2,32)
    const float* b1   = (const float*)d_in[3];   // (2,)
    const float* w2   = (const float*)d_in[4];   // (2,32)
    const float* b2   = (const float*)d_in[5];   // (2,)
    float* o = (float*)d_out;                    // (4,2,64,64)

    // workspace layout:
    float*  ws     = (float*)d_ws;
    float2* f2v    = (float2*)ws;                // 16384 float2 = 128 KB
    float4* stats4 = (float4*)(ws + 32768);      // 16384 float4 = 256 KB
    int*    bar    = (int*)(ws + 32768 + 65536); // 2 barrier regions x 4 KB

    // zero barrier state every launch (graph-capture-safe memset node)
    hipMemsetAsync(bar, 0, 8192, stream);

    fused_corr_kernel<<<NB, 256, 0, stream>>>(feat, outv, w1, b1, w2, b2,
                                              f2v, stats4, bar, o);
}

// Round 10
// 34.436 us; speedup vs baseline: 16.4692x; 16.4692x over previous
//
#include <hip/hip_runtime.h>

#define HW   4096
#define CIN  32
// scale in log2 domain: (1/sqrt(NCLASS)) * log2(e); NCLASS = 2
#define SCALE2 (0.70710678118654752f * 1.44269504088896340f)

// Raw v_exp_f32 (2^x): args bounded (|x| <~ 12), skip libm denormal fixup.
__device__ __forceinline__ float exp2_raw(float x) {
#if __has_builtin(__builtin_amdgcn_exp2f)
    return __builtin_amdgcn_exp2f(x);
#else
    float r;
    asm("v_exp_f32 %0, %1" : "=v"(r) : "v"(x));
    return r;
#endif
}

// ---------------- Kernel A: 1x1 conv projections, channel-split 4-way across waves
__global__ __launch_bounds__(256) void proj_kernel(
        const float* __restrict__ feat,
        const float* __restrict__ w1, const float* __restrict__ b1,
        const float* __restrict__ w2, const float* __restrict__ b2,
        float2* __restrict__ f1v, float2* __restrict__ f2v) {
    __shared__ float4 red[4][64];
    int tid = threadIdx.x;
    int pl = tid & 63;
    int cq = tid >> 6;                 // wave id = channel quarter
    int b = blockIdx.x;                // 256 blocks
    int n = b >> 6;
    int p = ((b & 63) << 6) + pl;
    const float* fbase = feat + ((size_t)n * CIN + cq * 8) * HW + p;
    float a10 = 0.f, a11 = 0.f, a20 = 0.f, a21 = 0.f;
#pragma unroll
    for (int c = 0; c < 8; ++c) {
        float v = fbase[(size_t)c * HW];
        a10 += v * w1[cq * 8 + c];
        a11 += v * w1[32 + cq * 8 + c];
        a20 += v * w2[cq * 8 + c];
        a21 += v * w2[32 + cq * 8 + c];
    }
    red[cq][pl] = make_float4(a10, a11, a20, a21);
    __syncthreads();
    if (tid < 64) {
        float4 r0 = red[0][tid], r1 = red[1][tid], r2 = red[2][tid], r3 = red[3][tid];
        int idx = n * HW + ((b & 63) << 6) + tid;
        f1v[idx] = make_float2(r0.x + r1.x + r2.x + r3.x + b1[0],
                               r0.y + r1.y + r2.y + r3.y + b1[1]);
        f2v[idx] = make_float2(r0.z + r1.z + r2.z + r3.z + b2[0],
                               r0.w + r1.w + r2.w + r3.w + b2[1]);
    }
}

// ---------------- Kernel B: l[p] = sum_q 2^(f1[p].f2[q]*s); write {f1*s, V0/l, V1/l}
// block = (n, 16 p's); f1 block-uniform -> SGPRs; wave wid streams its q-quarter
// as float4 (2 q per entry), per-lane coalesced, stride 64 entries.
__global__ __launch_bounds__(256) void rowstats_kernel(
        const float2* __restrict__ f1v, const float2* __restrict__ f2v,
        const float* __restrict__ outv, float4* __restrict__ stats4) {
    __shared__ float pB[4][17];        // padded: bank-safe cross-wave partials
    int tid = threadIdx.x;
    int lane = tid & 63;
    int wid = tid >> 6;
    int b = blockIdx.x;                // 1024 blocks
    int n = b >> 8;
    int pg = (b & 255) << 4;           // 16 p's
    int base = n * HW;

    int ub = __builtin_amdgcn_readfirstlane(base + pg);
    float f10[16], f11[16];
#pragma unroll
    for (int j = 0; j < 16; ++j) {     // uniform -> s_load, lives in SGPRs
        float2 f1 = f1v[ub + j];
        f10[j] = f1.x * SCALE2;
        f11[j] = f1.y * SCALE2;
    }
    const float4* f2b = (const float4*)(f2v + base) + wid * 512 + lane;
    float v[16];
#pragma unroll
    for (int j = 0; j < 16; ++j) v[j] = 0.f;
    float4 cur = f2b[0];
#pragma unroll
    for (int s = 0; s < 8; ++s) {
        float4 nxt = f2b[((s + 1) & 7) * 64];   // distance-1 rotation, const offsets
#pragma unroll
        for (int j = 0; j < 16; ++j) {
            float e0 = exp2_raw(f10[j] * cur.x + f11[j] * cur.y);
            float e1 = exp2_raw(f10[j] * cur.z + f11[j] * cur.w);
            v[j] += e0 + e1;
        }
        cur = nxt;
    }
    // recursive-halving exchange: after steps d=8,4,2,1 lane holds the sum over
    // its 16-lane group for idx = lane&15 (step d pins idx-bit log2(d) = lane-bit).
    {
        bool up8 = lane & 8;
#pragma unroll
        for (int k = 0; k < 8; ++k) {
            float send = up8 ? v[k] : v[k + 8];
            float recv = __shfl_xor(send, 8);
            v[k] = (up8 ? v[k + 8] : v[k]) + recv;
        }
        bool up4 = lane & 4;
#pragma unroll
        for (int k = 0; k < 4; ++k) {
            float send = up4 ? v[k] : v[k + 4];
            float recv = __shfl_xor(send, 4);
            v[k] = (up4 ? v[k + 4] : v[k]) + recv;
        }
        bool up2 = lane & 2;
#pragma unroll
        for (int k = 0; k < 2; ++k) {
            float send = up2 ? v[k] : v[k + 2];
            float recv = __shfl_xor(send, 2);
            v[k] = (up2 ? v[k + 2] : v[k]) + recv;
        }
        bool up1 = lane & 1;
        {
            float send = up1 ? v[0] : v[1];
            float recv = __shfl_xor(send, 1);
            v[0] = (up1 ? v[1] : v[0]) + recv;
        }
        v[0] += __shfl_xor(v[0], 16);
        v[0] += __shfl_xor(v[0], 32);
    }
    if (lane < 16) pB[wid][lane] = v[0];
    __syncthreads();
    if (tid < 16) {
        float lt = pB[0][tid] + pB[1][tid] + pB[2][tid] + pB[3][tid];
        float inv = 1.0f / lt;
        int pp = pg + tid;
        float2 f1 = f1v[base + pp];
        float v0 = outv[(n * 2 + 0) * HW + pp];
        float v1 = outv[(n * 2 + 1) * HW + pp];
        stats4[base + pp] = make_float4(f1.x * SCALE2, f1.y * SCALE2, v0 * inv, v1 * inv);
    }
}

// ---------------- Kernel C: o[c,q] = sum_p (V[c,p]/l[p]) * 2^(f1[p].f2[q]*s)
// block = (n, 16 q's); f2-of-q block-uniform -> SGPRs; wave wid streams its
// p-quarter of stats4, per-lane coalesced, stride 64 entries.
__global__ __launch_bounds__(256) void colout_kernel(
        const float2* __restrict__ f2v, const float4* __restrict__ stats4,
        float* __restrict__ o) {
    __shared__ float pC[4][33];        // padded: bank-safe cross-wave partials
    int tid = threadIdx.x;
    int lane = tid & 63;
    int wid = tid >> 6;
    int b = blockIdx.x;                // 1024 blocks
    int n = b >> 8;
    int qg = (b & 255) << 4;           // 16 q's
    int base = n * HW;

    int ub = __builtin_amdgcn_readfirstlane(base + qg);
    float g0[16], g1[16];
#pragma unroll
    for (int j = 0; j < 16; ++j) {     // uniform -> s_load (SCALE2 folded in stats4)
        float2 f2 = f2v[ub + j];
        g0[j] = f2.x;
        g1[j] = f2.y;
    }
    const float4* stb = stats4 + base + wid * 1024 + lane;
    // value layout: v[j] = (ch0, q j), v[16+j] = (ch1, q j)  -> idx = ch*16+q
    float v[32];
#pragma unroll
    for (int j = 0; j < 32; ++j) v[j] = 0.f;
    float4 cur = stb[0];
#pragma unroll
    for (int s = 0; s < 16; ++s) {
        float4 nxt = stb[((s + 1) & 15) * 64];  // distance-1 rotation, const offsets
#pragma unroll
        for (int j = 0; j < 16; ++j) {
            float e = exp2_raw(g0[j] * cur.x + g1[j] * cur.y);
            v[j]      += cur.z * e;
            v[16 + j] += cur.w * e;
        }
        cur = nxt;
    }
    // recursive-halving exchange over 32 values: steps d=16,8,4,2,1 pin
    // idx-bit log2(d) = lane-bit -> lane holds idx = lane&31; d=32 merges dups.
    {
        bool up16 = lane & 16;
#pragma unroll
        for (int k = 0; k < 16; ++k) {
            float send = up16 ? v[k] : v[k + 16];
            float recv = __shfl_xor(send, 16);
            v[k] = (up16 ? v[k + 16] : v[k]) + recv;
        }
        bool up8 = lane & 8;
#pragma unroll
        for (int k = 0; k < 8; ++k) {
            float send = up8 ? v[k] : v[k + 8];
            float recv = __shfl_xor(send, 8);
            v[k] = (up8 ? v[k + 8] : v[k]) + recv;
        }
        bool up4 = lane & 4;
#pragma unroll
        for (int k = 0; k < 4; ++k) {
            float send = up4 ? v[k] : v[k + 4];
            float recv = __shfl_xor(send, 4);
            v[k] = (up4 ? v[k + 4] : v[k]) + recv;
        }
        bool up2 = lane & 2;
#pragma unroll
        for (int k = 0; k < 2; ++k) {
            float send = up2 ? v[k] : v[k + 2];
            float recv = __shfl_xor(send, 2);
            v[k] = (up2 ? v[k + 2] : v[k]) + recv;
        }
        bool up1 = lane & 1;
        {
            float send = up1 ? v[0] : v[1];
            float recv = __shfl_xor(send, 1);
            v[0] = (up1 ? v[1] : v[0]) + recv;
        }
        v[0] += __shfl_xor(v[0], 32);
    }
    if (lane < 32) pC[wid][lane] = v[0];
    __syncthreads();
    if (tid < 32) {
        float r = pC[0][tid] + pC[1][tid] + pC[2][tid] + pC[3][tid];
        int ch = tid >> 4, qq = tid & 15;
        o[(n * 2 + ch) * HW + qg + qq] = r;
    }
}

extern "C" void kernel_launch(void* const* d_in, const int* in_sizes, int n_in,
                              void* d_out, int out_size, void* d_ws, size_t ws_size,
                              hipStream_t stream) {
    const float* feat = (const float*)d_in[0];   // (4,32,64,64)
    const float* outv = (const float*)d_in[1];   // (4,2,64,64)
    const float* w1   = (const float*)d_in[2];   // (2,32)
    const float* b1   = (const float*)d_in[3];   // (2,)
    const float* w2   = (const float*)d_in[4];   // (2,32)
    const float* b2   = (const float*)d_in[5];   // (2,)
    float* o = (float*)d_out;                    // (4,2,64,64)

    // workspace layout (512 KB used):
    float*  ws     = (float*)d_ws;
    float2* f1v    = (float2*)ws;                // 16384 float2 = 128 KB
    float2* f2v    = (float2*)(ws + 32768);      // 16384 float2 = 128 KB
    float4* stats4 = (float4*)(ws + 65536);      // 16384 float4 = 256 KB

    proj_kernel<<<256, 256, 0, stream>>>(feat, w1, b1, w2, b2, f1v, f2v);
    rowstats_kernel<<<1024, 256, 0, stream>>>(f1v, f2v, outv, stats4);
    colout_kernel<<<1024, 256, 0, stream>>>(f2v, stats4, o);
}